// Round 8
// baseline (298.172 us; speedup 1.0000x reference)
//
#include <hip/hip_runtime.h>
#include <hip/hip_bf16.h>
#include <stdint.h>

#define NH 12
#define DH 64
#define CC 768
#define NTOK 197
#define PFX 10
#define MKV 207
#define BB 64
#define MROWS (BB * NTOK)   // 12608
#define MPAD (99 * 128)     // 12672 rows (proj A padding)
#define NT_QKV 9            // 2304 / 256
#define MT_QKV 50           // ceil(12608/256)
#define MPAD2 (MT_QKV * 256) // 12800 rows (qkv A padding)
#define KV_PAD 208          // 13 * 16
#define KV_PAD2 224         // 7 * 32

typedef __attribute__((__ext_vector_type__(8))) short bf16x8;
typedef __attribute__((__ext_vector_type__(4))) float f32x4;

__device__ __forceinline__ ushort f2bf(float f) {
    union { float f; uint32_t u; } x; x.f = f;
    uint32_t u = x.u;
    return (ushort)((u + 0x7fffu + ((u >> 16) & 1u)) >> 16);
}

__device__ __forceinline__ void gload_lds16(const void* g, void* l) {
    __builtin_amdgcn_global_load_lds(
        (const __attribute__((address_space(1))) void*)g,
        (__attribute__((address_space(3))) void*)l, 16, 0, 0);
}

// Bijective chunked XCD swizzle (m204).
__device__ __forceinline__ int xcd_chunked(int orig, int nwg) {
    int q = nwg >> 3, r = nwg & 7;
    int xcd = orig & 7, rem = orig >> 3;
    return (xcd < r ? xcd * (q + 1) : r * (q + 1) + (xcd - r) * q) + rem;
}

// ---------------- convert fp32 -> bf16 (vectorized) ----------------
__global__ void cvt_bf16(const float* __restrict__ src, ushort* __restrict__ dst, int n4) {
    int i = blockIdx.x * 256 + threadIdx.x;
    if (i >= n4) return;
    float4 v = reinterpret_cast<const float4*>(src)[i];
    ushort4 o = make_ushort4(f2bf(v.x), f2bf(v.y), f2bf(v.z), f2bf(v.w));
    reinterpret_cast<ushort4*>(dst)[i] = o;
}

// ---------------- prompt prefix scatter ----------------
__global__ void prompt_scatter(const float* __restrict__ prompt,
                               ushort* __restrict__ kbuf, ushort* __restrict__ vt) {
    int i = blockIdx.x * 256 + threadIdx.x;
    if (i >= BB * 2 * PFX * NH * DH) return;
    int d = i & 63;
    int h = (i >> 6) % NH;
    int p = (i / (64 * NH)) % PFX;
    int s = (i / (64 * NH * PFX)) & 1;
    int b = i / (64 * NH * PFX * 2);
    ushort val = f2bf(prompt[i]);
    int bh = b * NH + h;
    if (s == 0) kbuf[(bh * KV_PAD + p) * DH + d] = val;
    else        vt[(bh * DH + d) * KV_PAD2 + p] = val;
}

// ============ GEMM-QKV: 256x256 tile, BK=64, 8 waves, counted-vmcnt pipeline ======
// C[M,N] = A[M,K] @ B[N,K]^T. LDS: 2 dbuf x (A[256][64] + B[256][64]) bf16 = 128 KiB.
// Per K-tile: 2 phases (mi-halves), each {stage-next, vmcnt(8), barrier, ds_read,
// MFMA x32 (setprio), barrier}. Stage stream runs 2 phases ahead of consumption.
// Swizzle (write side, per 64x64 unit): LDS[row][cb] = G[row][cb ^ (row&7)],
// cb = 16-byte colblock 0..7. Read side: logical colblock c = ks*4+g is at LDS
// colblock c ^ (row&7) (row&7 == lr&7 for all fragment rows). 8 distinct
// colblocks x 8 lanes each -> all 32 banks busy = ds_read_b128 floor.

#define STAGE6(kt) {                                                              \
    const int bsel = (kt) & 1; const int koff = (kt) * 64;                        \
    gload_lds16(pA[0] + koff, &lds[bsel][0][0 * 4096 + w * 512]);                 \
    gload_lds16(pA[2] + koff, &lds[bsel][0][2 * 4096 + w * 512]);                 \
    gload_lds16(pB[0] + koff, &lds[bsel][1][0 * 4096 + w * 512]);                 \
    gload_lds16(pB[1] + koff, &lds[bsel][1][1 * 4096 + w * 512]);                 \
    gload_lds16(pB[2] + koff, &lds[bsel][1][2 * 4096 + w * 512]);                 \
    gload_lds16(pB[3] + koff, &lds[bsel][1][3 * 4096 + w * 512]); }

#define STAGE2(kt) {                                                              \
    const int bsel = (kt) & 1; const int koff = (kt) * 64;                        \
    gload_lds16(pA[1] + koff, &lds[bsel][0][1 * 4096 + w * 512]);                 \
    gload_lds16(pA[3] + koff, &lds[bsel][0][3 * 4096 + w * 512]); }

#define PHASE(t, p, VMSTR, DOSTAGE) {                                             \
    if (DOSTAGE) { if ((p) == 0) STAGE6((t) + 1) else STAGE2((t) + 1) }           \
    asm volatile("s_waitcnt vmcnt(" VMSTR ")" ::: "memory");                      \
    __builtin_amdgcn_s_barrier();                                                 \
    __builtin_amdgcn_sched_barrier(0);                                            \
    const ushort* Ab = &lds[(t) & 1][0][0];                                       \
    const ushort* Bb = &lds[(t) & 1][1][0];                                       \
    bf16x8 af[4][2], bf[4][2];                                                    \
    _Pragma("unroll") for (int i = 0; i < 4; ++i)                                 \
      _Pragma("unroll") for (int ks = 0; ks < 2; ++ks)                            \
        af[i][ks] = *reinterpret_cast<const bf16x8*>(                             \
            &Ab[(wm * 128 + ((p) * 4 + i) * 16 + lr) * 64 + coff[ks]]);           \
    _Pragma("unroll") for (int n = 0; n < 4; ++n)                                 \
      _Pragma("unroll") for (int ks = 0; ks < 2; ++ks)                            \
        bf[n][ks] = *reinterpret_cast<const bf16x8*>(                             \
            &Bb[(wn * 64 + n * 16 + lr) * 64 + coff[ks]]);                        \
    __builtin_amdgcn_s_setprio(1);                                                \
    _Pragma("unroll") for (int ks = 0; ks < 2; ++ks)                              \
      _Pragma("unroll") for (int i = 0; i < 4; ++i)                               \
        _Pragma("unroll") for (int n = 0; n < 4; ++n)                             \
          acc[(p) * 4 + i][n] = __builtin_amdgcn_mfma_f32_16x16x32_bf16(          \
              af[i][ks], bf[n][ks], acc[(p) * 4 + i][n], 0, 0, 0);                \
    __builtin_amdgcn_s_setprio(0);                                                \
    __builtin_amdgcn_s_barrier();                                                 \
    __builtin_amdgcn_sched_barrier(0);                                            \
}

__global__ __launch_bounds__(512, 2) void gemm_qkv8(const ushort* __restrict__ A,
                                                    const ushort* __restrict__ Bw,
                                                    ushort* __restrict__ qbuf,
                                                    ushort* __restrict__ kbuf,
                                                    ushort* __restrict__ vt) {
    __shared__ __align__(16) ushort lds[2][2][256 * 64];   // 128 KiB
    const int tid  = threadIdx.x;
    const int lane = tid & 63;
    const int w    = tid >> 6;              // wave 0..7
    const int wm = w >> 2, wn = w & 3;      // 2M x 4N wave grid
    const int g = lane >> 4, lr = lane & 15;
    const int wgid = xcd_chunked(blockIdx.x, gridDim.x);
    const int row0 = (wgid / NT_QKV) * 256;
    const int col0 = (wgid % NT_QKV) * 256;

    // staging: thread tid covers unit bytes [tid*16, tid*16+16) = row tid/8,
    // LDS colblock tid&7; global source colblock = (tid&7) ^ (row&7).
    const int sr  = tid >> 3;                                  // 0..63
    const int scb = (((tid & 7) ^ ((tid >> 3) & 7)) << 3);     // ushort offset
    // read-side: logical colblock c=ks*4+g lives at LDS colblock c^(lr&7)
    const int lr7 = lr & 7;
    int coff[2];
    coff[0] = ((0 * 4 + g) ^ lr7) << 3;
    coff[1] = ((1 * 4 + g) ^ lr7) << 3;

    const ushort* pA[4];
    #pragma unroll
    for (int q = 0; q < 4; ++q)
        pA[q] = A + (size_t)(row0 + q * 64 + sr) * CC + scb;
    const ushort* pB[4];
    #pragma unroll
    for (int j = 0; j < 4; ++j)
        pB[j] = Bw + (size_t)(col0 + j * 64 + sr) * CC + scb;

    f32x4 acc[8][4] = {};

    // prologue: tile 0 fully staged (first-needed 6 units first)
    STAGE6(0)
    STAGE2(0)

    // 12 K-tiles (K=768, BK=64); stage while t+1 exists
    for (int t = 0; t < 11; ++t) {
        PHASE(t, 0, "8", true)
        PHASE(t, 1, "8", true)
    }
    PHASE(11, 0, "2", false)
    PHASE(11, 1, "0", false)

    // epilogue: scatter q/k/vt
    #pragma unroll
    for (int ni = 0; ni < 4; ++ni) {
        int f = col0 + wn * 64 + ni * 16 + lr;     // 0..2303
        int s   = f / CC;
        int rem = f - s * CC;
        int h = rem >> 6, d = rem & 63;
        #pragma unroll
        for (int mi = 0; mi < 8; ++mi) {
            #pragma unroll
            for (int rr = 0; rr < 4; ++rr) {
                int r = row0 + wm * 128 + mi * 16 + g * 4 + rr;
                if (r >= MROWS) continue;
                int b = r / NTOK;
                int n = r - b * NTOK;
                ushort val = f2bf(acc[mi][ni][rr]);
                int bh = b * NH + h;
                if (s == 0)      qbuf[(bh * KV_PAD + n) * DH + d] = val;
                else if (s == 1) kbuf[(bh * KV_PAD + n + PFX) * DH + d] = val;
                else             vt[(bh * DH + d) * KV_PAD2 + n + PFX] = val;
            }
        }
    }
}

// ---------------- GEMM-proj: 2-phase double-buffered 128x128 (unchanged) --------
#define GEMM_PRE(A_, B_, KDIM, NTILES)                                               \
    __shared__ __align__(16) ushort Alds0[128 * 32];                                 \
    __shared__ __align__(16) ushort Blds0[128 * 32];                                 \
    __shared__ __align__(16) ushort Alds1[128 * 32];                                 \
    __shared__ __align__(16) ushort Blds1[128 * 32];                                 \
    const int tid  = threadIdx.x;                                                    \
    const int lane = tid & 63;                                                       \
    const int wave = tid >> 6;                                                       \
    const int wm = wave >> 1, wn = wave & 1;                                         \
    const int g = lane >> 4, lr = lane & 15;                                         \
    const int wgid = xcd_chunked(blockIdx.x, gridDim.x);                             \
    const int row0 = (wgid / (NTILES)) * 128;                                        \
    const int col0 = (wgid % (NTILES)) * 128;                                        \
    const int srow = lane >> 2;                                                      \
    const int scol = (lane & 3) * 8;                                                 \
    const ushort* gA0 = &(A_)[(size_t)(row0 + wave * 16 + srow) * (KDIM) + scol];    \
    const ushort* gA1 = gA0 + (size_t)64 * (KDIM);                                   \
    const ushort* gB0 = &(B_)[(size_t)(col0 + wave * 16 + srow) * (KDIM) + scol];    \
    const ushort* gB1 = gB0 + (size_t)64 * (KDIM);                                   \
    f32x4 acc[4][4] = {};

#define GEMM_STAGE(AB, BB_, KOFF)                                                    \
    gload_lds16(gA0 + (KOFF), &(AB)[(wave * 16) * 32]);                              \
    gload_lds16(gA1 + (KOFF), &(AB)[(64 + wave * 16) * 32]);                         \
    gload_lds16(gB0 + (KOFF), &(BB_)[(wave * 16) * 32]);                             \
    gload_lds16(gB1 + (KOFF), &(BB_)[(64 + wave * 16) * 32]);

#define GEMM_COMPUTE(AB, BB_)                                                        \
    {                                                                                \
        bf16x8 af[4], bfr[4];                                                        \
        _Pragma("unroll")                                                            \
        for (int i = 0; i < 4; ++i)                                                  \
            af[i] = *reinterpret_cast<const bf16x8*>(&(AB)[(wm * 64 + i * 16 + lr) * 32 + g * 8]); \
        _Pragma("unroll")                                                            \
        for (int i = 0; i < 4; ++i)                                                  \
            bfr[i] = *reinterpret_cast<const bf16x8*>(&(BB_)[(wn * 64 + i * 16 + lr) * 32 + g * 8]); \
        _Pragma("unroll")                                                            \
        for (int mi = 0; mi < 4; ++mi)                                               \
            _Pragma("unroll")                                                        \
            for (int ni = 0; ni < 4; ++ni)                                           \
                acc[mi][ni] = __builtin_amdgcn_mfma_f32_16x16x32_bf16(af[mi], bfr[ni], acc[mi][ni], 0, 0, 0); \
    }

#define GEMM_MAIN(A_, B_, KDIM, NTILES)                                              \
    GEMM_PRE(A_, B_, KDIM, NTILES)                                                   \
    GEMM_STAGE(Alds0, Blds0, 0)                                                      \
    __syncthreads();                                                                 \
    for (int k0 = 0; k0 < (KDIM); k0 += 64) {                                        \
        GEMM_STAGE(Alds1, Blds1, k0 + 32)                                            \
        GEMM_COMPUTE(Alds0, Blds0)                                                   \
        __syncthreads();                                                             \
        if (k0 + 64 < (KDIM)) { GEMM_STAGE(Alds0, Blds0, k0 + 64) }                  \
        GEMM_COMPUTE(Alds1, Blds1)                                                   \
        __syncthreads();                                                             \
    }

__global__ __launch_bounds__(256) void gemm_proj(const ushort* __restrict__ A,
                                                 const ushort* __restrict__ Bw,
                                                 const float* __restrict__ bias,
                                                 float* __restrict__ out) {
    GEMM_MAIN(A, Bw, CC, 6)
    #pragma unroll
    for (int ni = 0; ni < 4; ++ni) {
        int o = col0 + wn * 64 + ni * 16 + lr;
        float bs = bias[o];
        #pragma unroll
        for (int mi = 0; mi < 4; ++mi) {
            #pragma unroll
            for (int rr = 0; rr < 4; ++rr) {
                int r = row0 + wm * 64 + mi * 16 + g * 4 + rr;
                if (r >= MROWS) continue;
                out[(size_t)r * CC + o] = acc[mi][ni][rr] + bs;
            }
        }
    }
}

// ---------------- attention (unchanged from round 4) ----------------
__global__ __launch_bounds__(64) void attn(const ushort* __restrict__ qbuf,
                                           const ushort* __restrict__ kbuf,
                                           const ushort* __restrict__ vt,
                                           ushort* __restrict__ aout) {
    __shared__ __align__(16) ushort Plds[16][232];
    const int lane = threadIdx.x;
    const int g = lane >> 4, lr = lane & 15;
    const int wgid = xcd_chunked(blockIdx.x, gridDim.x);
    const int bh = wgid / 13;            // 0..767
    const int qt = wgid % 13;            // 0..12
    const int b = bh / NH;
    const int h = bh - b * NH;
    const ushort* Q  = qbuf + (size_t)bh * KV_PAD * DH;
    const ushort* Kb = kbuf + (size_t)bh * KV_PAD * DH;
    const ushort* V  = vt   + (size_t)bh * DH * KV_PAD2;

    bf16x8 qf[2];
    #pragma unroll
    for (int kc = 0; kc < 2; ++kc)
        qf[kc] = *reinterpret_cast<const bf16x8*>(&Q[(qt * 16 + lr) * DH + kc * 32 + g * 8]);

    f32x4 s[13];
    __builtin_amdgcn_s_setprio(1);
    #pragma unroll
    for (int t = 0; t < 13; ++t) {
        f32x4 a = {};
        #pragma unroll
        for (int kc = 0; kc < 2; ++kc) {
            bf16x8 kf = *reinterpret_cast<const bf16x8*>(&Kb[(t * 16 + lr) * DH + kc * 32 + g * 8]);
            a = __builtin_amdgcn_mfma_f32_16x16x32_bf16(kf, qf[kc], a, 0, 0, 0);
        }
        s[t] = a;
    }
    __builtin_amdgcn_s_setprio(0);

    float m = -1e30f;
    #pragma unroll
    for (int t = 0; t < 13; ++t) {
        #pragma unroll
        for (int rr = 0; rr < 4; ++rr) {
            int kv = t * 16 + g * 4 + rr;
            float v = (kv < MKV) ? s[t][rr] : -1e30f;
            s[t][rr] = v;
            m = fmaxf(m, v);
        }
    }
    m = fmaxf(m, __shfl_xor(m, 16));
    m = fmaxf(m, __shfl_xor(m, 32));

    const float cs = 0.125f * 1.4426950408889634f;
    float sum = 0.f;
    #pragma unroll
    for (int t = 0; t < 13; ++t) {
        #pragma unroll
        for (int rr = 0; rr < 4; ++rr) {
            float p = exp2f((s[t][rr] - m) * cs);
            s[t][rr] = p;
            sum += p;
        }
    }
    sum += __shfl_xor(sum, 16);
    sum += __shfl_xor(sum, 32);
    float inv = 1.0f / sum;

    {
        int row = lane >> 2;
        int col = 208 + (lane & 3) * 4;
        *reinterpret_cast<ushort4*>(&Plds[row][col]) = make_ushort4(0, 0, 0, 0);
    }
    #pragma unroll
    for (int t = 0; t < 13; ++t) {
        #pragma unroll
        for (int rr = 0; rr < 4; ++rr)
            Plds[lr][t * 16 + g * 4 + rr] = f2bf(s[t][rr] * inv);
    }
    __syncthreads();

    const int q = qt * 16 + lr;
    #pragma unroll
    for (int dt = 0; dt < 4; ++dt) {
        f32x4 o = {};
        __builtin_amdgcn_s_setprio(1);
        #pragma unroll
        for (int kc = 0; kc < 7; ++kc) {
            bf16x8 vf = *reinterpret_cast<const bf16x8*>(&V[(dt * 16 + lr) * KV_PAD2 + kc * 32 + g * 8]);
            bf16x8 pf = *reinterpret_cast<const bf16x8*>(&Plds[lr][kc * 32 + g * 8]);
            o = __builtin_amdgcn_mfma_f32_16x16x32_bf16(vf, pf, o, 0, 0, 0);
        }
        __builtin_amdgcn_s_setprio(0);
        if (q < NTOK) {
            ushort4 st = make_ushort4(f2bf(o[0]), f2bf(o[1]), f2bf(o[2]), f2bf(o[3]));
            int r = b * NTOK + q;
            *reinterpret_cast<ushort4*>(&aout[(size_t)r * CC + h * 64 + dt * 16 + g * 4]) = st;
        }
    }
}

// ---------------- launch ----------------
extern "C" void kernel_launch(void* const* d_in, const int* in_sizes, int n_in,
                              void* d_out, int out_size, void* d_ws, size_t ws_size,
                              hipStream_t stream) {
    const float* x      = (const float*)d_in[0];
    const float* prompt = (const float*)d_in[1];
    const float* qkv_w  = (const float*)d_in[2];
    const float* proj_w = (const float*)d_in[3];
    const float* proj_b = (const float*)d_in[4];
    float* out = (float*)d_out;

    char* ws = (char*)d_ws;
    ushort* Xb = (ushort*)(ws + 0);          // MPAD2*768*2      = 19,660,800
    ushort* Wq = (ushort*)(ws + 19660800);   // 2304*768*2       =  3,538,944
    ushort* Wp = (ushort*)(ws + 23199744);   // 768*768*2        =  1,179,648
    ushort* qb = (ushort*)(ws + 24379392);   // 768*208*64*2     = 20,447,232
    ushort* kb = (ushort*)(ws + 44826624);   // 768*208*64*2     = 20,447,232
    ushort* vt = (ushort*)(ws + 65273856);   // 768*64*224*2     = 22,020,096
    ushort* ao = (ushort*)(ws + 87293952);   // MPAD*768*2       = 19,464,192
    // total 106,758,144 bytes

    cvt_bf16<<<dim3((MROWS * CC / 4 + 255) / 256), 256, 0, stream>>>(x, Xb, MROWS * CC / 4);
    cvt_bf16<<<dim3((3 * CC * CC / 4 + 255) / 256), 256, 0, stream>>>(qkv_w, Wq, 3 * CC * CC / 4);
    cvt_bf16<<<dim3((CC * CC / 4 + 255) / 256), 256, 0, stream>>>(proj_w, Wp, CC * CC / 4);
    prompt_scatter<<<dim3((BB * 2 * PFX * NH * DH + 255) / 256), 256, 0, stream>>>(prompt, kb, vt);

    gemm_qkv8<<<dim3(MT_QKV * NT_QKV), 512, 0, stream>>>(Xb, Wq, qb, kb, vt);
    attn<<<dim3(13 * BB * NH), 64, 0, stream>>>(qb, kb, vt, ao);
    gemm_proj<<<dim3(99 * 6), 256, 0, stream>>>(ao, Wp, proj_b, out);
}

// Round 9
// 278.342 us; speedup vs baseline: 1.0712x; 1.0712x over previous
//
#include <hip/hip_runtime.h>
#include <hip/hip_bf16.h>
#include <stdint.h>

#define NH 12
#define DH 64
#define CC 768
#define NTOK 197
#define PFX 10
#define MKV 207
#define BB 64
#define MROWS (BB * NTOK)   // 12608
#define MPAD (99 * 128)     // 12672 rows (proj A padding)
#define NT_QKV 9            // 2304 / 256
#define MT_QKV 50           // ceil(12608/256)
#define MPAD2 (MT_QKV * 256) // 12800 rows (qkv A padding)
#define KV_PAD 208          // 13 * 16
#define KV_PAD2 224         // 7 * 32
#define VSTRIDE 232         // LDS V/P stride: odd multiple of 8 -> conflict-free b128

typedef __attribute__((__ext_vector_type__(8))) short bf16x8;
typedef __attribute__((__ext_vector_type__(4))) float f32x4;

__device__ __forceinline__ ushort f2bf(float f) {
    union { float f; uint32_t u; } x; x.f = f;
    uint32_t u = x.u;
    return (ushort)((u + 0x7fffu + ((u >> 16) & 1u)) >> 16);
}

__device__ __forceinline__ void gload_lds16(const void* g, void* l) {
    __builtin_amdgcn_global_load_lds(
        (const __attribute__((address_space(1))) void*)g,
        (__attribute__((address_space(3))) void*)l, 16, 0, 0);
}

// Bijective chunked XCD swizzle (m204).
__device__ __forceinline__ int xcd_chunked(int orig, int nwg) {
    int q = nwg >> 3, r = nwg & 7;
    int xcd = orig & 7, rem = orig >> 3;
    return (xcd < r ? xcd * (q + 1) : r * (q + 1) + (xcd - r) * q) + rem;
}

// ---------------- convert fp32 -> bf16 (vectorized) ----------------
__global__ void cvt_bf16(const float* __restrict__ src, ushort* __restrict__ dst, int n4) {
    int i = blockIdx.x * 256 + threadIdx.x;
    if (i >= n4) return;
    float4 v = reinterpret_cast<const float4*>(src)[i];
    ushort4 o = make_ushort4(f2bf(v.x), f2bf(v.y), f2bf(v.z), f2bf(v.w));
    reinterpret_cast<ushort4*>(dst)[i] = o;
}

// ---------------- prompt prefix scatter ----------------
__global__ void prompt_scatter(const float* __restrict__ prompt,
                               ushort* __restrict__ kbuf, ushort* __restrict__ vt) {
    int i = blockIdx.x * 256 + threadIdx.x;
    if (i >= BB * 2 * PFX * NH * DH) return;
    int d = i & 63;
    int h = (i >> 6) % NH;
    int p = (i / (64 * NH)) % PFX;
    int s = (i / (64 * NH * PFX)) & 1;
    int b = i / (64 * NH * PFX * 2);
    ushort val = f2bf(prompt[i]);
    int bh = b * NH + h;
    if (s == 0) kbuf[(bh * KV_PAD + p) * DH + d] = val;
    else        vt[(bh * DH + d) * KV_PAD2 + p] = val;
}

// ============ GEMM-QKV: 256x256 tile, BK=64, 8 waves, counted-vmcnt pipeline ======
#define STAGE6(kt) {                                                              \
    const int bsel = (kt) & 1; const int koff = (kt) * 64;                        \
    gload_lds16(pA[0] + koff, &lds[bsel][0][0 * 4096 + w * 512]);                 \
    gload_lds16(pA[2] + koff, &lds[bsel][0][2 * 4096 + w * 512]);                 \
    gload_lds16(pB[0] + koff, &lds[bsel][1][0 * 4096 + w * 512]);                 \
    gload_lds16(pB[1] + koff, &lds[bsel][1][1 * 4096 + w * 512]);                 \
    gload_lds16(pB[2] + koff, &lds[bsel][1][2 * 4096 + w * 512]);                 \
    gload_lds16(pB[3] + koff, &lds[bsel][1][3 * 4096 + w * 512]); }

#define STAGE2(kt) {                                                              \
    const int bsel = (kt) & 1; const int koff = (kt) * 64;                        \
    gload_lds16(pA[1] + koff, &lds[bsel][0][1 * 4096 + w * 512]);                 \
    gload_lds16(pA[3] + koff, &lds[bsel][0][3 * 4096 + w * 512]); }

#define PHASE(t, p, VMSTR, DOSTAGE) {                                             \
    if (DOSTAGE) { if ((p) == 0) STAGE6((t) + 1) else STAGE2((t) + 1) }           \
    asm volatile("s_waitcnt vmcnt(" VMSTR ")" ::: "memory");                      \
    __builtin_amdgcn_s_barrier();                                                 \
    __builtin_amdgcn_sched_barrier(0);                                            \
    const ushort* Ab = &lds[(t) & 1][0][0];                                       \
    const ushort* Bb = &lds[(t) & 1][1][0];                                       \
    bf16x8 af[4][2], bf[4][2];                                                    \
    _Pragma("unroll") for (int i = 0; i < 4; ++i)                                 \
      _Pragma("unroll") for (int ks = 0; ks < 2; ++ks)                            \
        af[i][ks] = *reinterpret_cast<const bf16x8*>(                             \
            &Ab[(wm * 128 + ((p) * 4 + i) * 16 + lr) * 64 + coff[ks]]);           \
    _Pragma("unroll") for (int n = 0; n < 4; ++n)                                 \
      _Pragma("unroll") for (int ks = 0; ks < 2; ++ks)                            \
        bf[n][ks] = *reinterpret_cast<const bf16x8*>(                             \
            &Bb[(wn * 64 + n * 16 + lr) * 64 + coff[ks]]);                        \
    __builtin_amdgcn_s_setprio(1);                                                \
    _Pragma("unroll") for (int ks = 0; ks < 2; ++ks)                              \
      _Pragma("unroll") for (int i = 0; i < 4; ++i)                               \
        _Pragma("unroll") for (int n = 0; n < 4; ++n)                             \
          acc[(p) * 4 + i][n] = __builtin_amdgcn_mfma_f32_16x16x32_bf16(          \
              af[i][ks], bf[n][ks], acc[(p) * 4 + i][n], 0, 0, 0);                \
    __builtin_amdgcn_s_setprio(0);                                                \
    __builtin_amdgcn_s_barrier();                                                 \
    __builtin_amdgcn_sched_barrier(0);                                            \
}

__global__ __launch_bounds__(512, 2) void gemm_qkv8(const ushort* __restrict__ A,
                                                    const ushort* __restrict__ Bw,
                                                    ushort* __restrict__ qbuf,
                                                    ushort* __restrict__ kbuf,
                                                    ushort* __restrict__ vt) {
    __shared__ __align__(16) ushort lds[2][2][256 * 64];   // 128 KiB
    const int tid  = threadIdx.x;
    const int lane = tid & 63;
    const int w    = tid >> 6;              // wave 0..7
    const int wm = w >> 2, wn = w & 3;      // 2M x 4N wave grid
    const int g = lane >> 4, lr = lane & 15;
    const int wgid = xcd_chunked(blockIdx.x, gridDim.x);
    const int row0 = (wgid / NT_QKV) * 256;
    const int col0 = (wgid % NT_QKV) * 256;

    const int sr  = tid >> 3;                                  // 0..63
    const int scb = (((tid & 7) ^ ((tid >> 3) & 7)) << 3);     // ushort offset
    const int lr7 = lr & 7;
    int coff[2];
    coff[0] = ((0 * 4 + g) ^ lr7) << 3;
    coff[1] = ((1 * 4 + g) ^ lr7) << 3;

    const ushort* pA[4];
    #pragma unroll
    for (int q = 0; q < 4; ++q)
        pA[q] = A + (size_t)(row0 + q * 64 + sr) * CC + scb;
    const ushort* pB[4];
    #pragma unroll
    for (int j = 0; j < 4; ++j)
        pB[j] = Bw + (size_t)(col0 + j * 64 + sr) * CC + scb;

    f32x4 acc[8][4] = {};

    STAGE6(0)
    STAGE2(0)

    for (int t = 0; t < 11; ++t) {
        PHASE(t, 0, "8", true)
        PHASE(t, 1, "8", true)
    }
    PHASE(11, 0, "2", false)
    PHASE(11, 1, "0", false)

    #pragma unroll
    for (int ni = 0; ni < 4; ++ni) {
        int f = col0 + wn * 64 + ni * 16 + lr;     // 0..2303
        int s   = f / CC;
        int rem = f - s * CC;
        int h = rem >> 6, d = rem & 63;
        #pragma unroll
        for (int mi = 0; mi < 8; ++mi) {
            #pragma unroll
            for (int rr = 0; rr < 4; ++rr) {
                int r = row0 + wm * 128 + mi * 16 + g * 4 + rr;
                if (r >= MROWS) continue;
                int b = r / NTOK;
                int n = r - b * NTOK;
                ushort val = f2bf(acc[mi][ni][rr]);
                int bh = b * NH + h;
                if (s == 0)      qbuf[(bh * KV_PAD + n) * DH + d] = val;
                else if (s == 1) kbuf[(bh * KV_PAD + n + PFX) * DH + d] = val;
                else             vt[(bh * DH + d) * KV_PAD2 + n + PFX] = val;
            }
        }
    }
}

// ---------------- GEMM-proj: 2-phase double-buffered 128x128 ----------------
#define GEMM_PRE(A_, B_, KDIM, NTILES)                                               \
    __shared__ __align__(16) ushort Alds0[128 * 32];                                 \
    __shared__ __align__(16) ushort Blds0[128 * 32];                                 \
    __shared__ __align__(16) ushort Alds1[128 * 32];                                 \
    __shared__ __align__(16) ushort Blds1[128 * 32];                                 \
    const int tid  = threadIdx.x;                                                    \
    const int lane = tid & 63;                                                       \
    const int wave = tid >> 6;                                                       \
    const int wm = wave >> 1, wn = wave & 1;                                         \
    const int g = lane >> 4, lr = lane & 15;                                         \
    const int wgid = xcd_chunked(blockIdx.x, gridDim.x);                             \
    const int row0 = (wgid / (NTILES)) * 128;                                        \
    const int col0 = (wgid % (NTILES)) * 128;                                        \
    const int srow = lane >> 2;                                                      \
    const int scol = (lane & 3) * 8;                                                 \
    const ushort* gA0 = &(A_)[(size_t)(row0 + wave * 16 + srow) * (KDIM) + scol];    \
    const ushort* gA1 = gA0 + (size_t)64 * (KDIM);                                   \
    const ushort* gB0 = &(B_)[(size_t)(col0 + wave * 16 + srow) * (KDIM) + scol];    \
    const ushort* gB1 = gB0 + (size_t)64 * (KDIM);                                   \
    f32x4 acc[4][4] = {};

#define GEMM_STAGE(AB, BB_, KOFF)                                                    \
    gload_lds16(gA0 + (KOFF), &(AB)[(wave * 16) * 32]);                              \
    gload_lds16(gA1 + (KOFF), &(AB)[(64 + wave * 16) * 32]);                         \
    gload_lds16(gB0 + (KOFF), &(BB_)[(wave * 16) * 32]);                             \
    gload_lds16(gB1 + (KOFF), &(BB_)[(64 + wave * 16) * 32]);

#define GEMM_COMPUTE(AB, BB_)                                                        \
    {                                                                                \
        bf16x8 af[4], bfr[4];                                                        \
        _Pragma("unroll")                                                            \
        for (int i = 0; i < 4; ++i)                                                  \
            af[i] = *reinterpret_cast<const bf16x8*>(&(AB)[(wm * 64 + i * 16 + lr) * 32 + g * 8]); \
        _Pragma("unroll")                                                            \
        for (int i = 0; i < 4; ++i)                                                  \
            bfr[i] = *reinterpret_cast<const bf16x8*>(&(BB_)[(wn * 64 + i * 16 + lr) * 32 + g * 8]); \
        _Pragma("unroll")                                                            \
        for (int mi = 0; mi < 4; ++mi)                                               \
            _Pragma("unroll")                                                        \
            for (int ni = 0; ni < 4; ++ni)                                           \
                acc[mi][ni] = __builtin_amdgcn_mfma_f32_16x16x32_bf16(af[mi], bfr[ni], acc[mi][ni], 0, 0, 0); \
    }

#define GEMM_MAIN(A_, B_, KDIM, NTILES)                                              \
    GEMM_PRE(A_, B_, KDIM, NTILES)                                                   \
    GEMM_STAGE(Alds0, Blds0, 0)                                                      \
    __syncthreads();                                                                 \
    for (int k0 = 0; k0 < (KDIM); k0 += 64) {                                        \
        GEMM_STAGE(Alds1, Blds1, k0 + 32)                                            \
        GEMM_COMPUTE(Alds0, Blds0)                                                   \
        __syncthreads();                                                             \
        if (k0 + 64 < (KDIM)) { GEMM_STAGE(Alds0, Blds0, k0 + 64) }                  \
        GEMM_COMPUTE(Alds1, Blds1)                                                   \
        __syncthreads();                                                             \
    }

__global__ __launch_bounds__(256) void gemm_proj(const ushort* __restrict__ A,
                                                 const ushort* __restrict__ Bw,
                                                 const float* __restrict__ bias,
                                                 float* __restrict__ out) {
    GEMM_MAIN(A, Bw, CC, 6)
    #pragma unroll
    for (int ni = 0; ni < 4; ++ni) {
        int o = col0 + wn * 64 + ni * 16 + lr;
        float bs = bias[o];
        #pragma unroll
        for (int mi = 0; mi < 4; ++mi) {
            #pragma unroll
            for (int rr = 0; rr < 4; ++rr) {
                int r = row0 + wm * 64 + mi * 16 + g * 4 + rr;
                if (r >= MROWS) continue;
                out[(size_t)r * CC + o] = acc[mi][ni][rr] + bs;
            }
        }
    }
}

// ================= fused attention: one 8-wave block per (b,h) =================
// K[208][64] staged via XOR-swizzled global_load_lds (LDS[row][cb]=G[row][cb^(row&7)]);
// V^T reg-staged into [64][VSTRIDE=232] padded LDS (stride = odd*8 -> the 8 distinct
// per-lane rows cover all 32 banks, 2-way alias only = free). Per-wave private P
// buffer [16][232]. Each wave computes q-tiles {w, w+8}. Swapped QK^T softmax
// unchanged from the verified 1-wave kernel.
__global__ __launch_bounds__(512, 2) void attn_bh(const ushort* __restrict__ qbuf,
                                                  const ushort* __restrict__ kbuf,
                                                  const ushort* __restrict__ vt,
                                                  ushort* __restrict__ aout) {
    __shared__ __align__(16) ushort Klds[KV_PAD * DH];        // 26,624 B
    __shared__ __align__(16) ushort Vlds[DH * VSTRIDE];       // 29,696 B
    __shared__ __align__(16) ushort Plds[8 * 16 * VSTRIDE];   // 59,392 B
    const int tid  = threadIdx.x;
    const int lane = tid & 63;
    const int w    = tid >> 6;
    const int g = lane >> 4, lr = lane & 15;
    const int bh = blockIdx.x;               // 0..767
    const int b = bh / NH, h = bh - b * NH;

    // ---- stage K (26 x 1KB units, XOR-swizzled source, linear LDS dest) ----
    const ushort* pKsrc = kbuf + (size_t)bh * KV_PAD * DH
                        + (lane >> 3) * DH + (((lane & 7) ^ (lane >> 3)) << 3);
    #pragma unroll
    for (int u = 0; u < 4; ++u) {
        int uu = w + u * 8;
        if (uu < 26) gload_lds16(pKsrc + uu * 512, &Klds[uu * 512]);
    }

    // ---- stage V^T into padded LDS (reg path; 1792 x 16B units) ----
    const int4* vsrc = reinterpret_cast<const int4*>(vt + (size_t)bh * DH * KV_PAD2);
    #pragma unroll
    for (int k = 0; k < 4; ++k) {
        int u = tid + 512 * k;
        if (u < DH * (KV_PAD2 / 8)) {        // 1792
            int4 d = vsrc[u];
            int row  = u / (KV_PAD2 / 8);    // /28
            int colu = u - row * (KV_PAD2 / 8);
            *reinterpret_cast<int4*>(&Vlds[row * VSTRIDE + colu * 8]) = d;
        }
    }

    // ---- prefetch Q fragments for this wave's tiles (independent of LDS) ----
    const ushort* Q = qbuf + (size_t)bh * KV_PAD * DH;
    const int qt0 = w, qt1 = w + 8;          // qt1 valid iff w < 5
    bf16x8 qf0[2], qf1[2];
    #pragma unroll
    for (int kc = 0; kc < 2; ++kc)
        qf0[kc] = *reinterpret_cast<const bf16x8*>(&Q[(qt0 * 16 + lr) * DH + kc * 32 + g * 8]);
    if (qt1 < 13) {
        #pragma unroll
        for (int kc = 0; kc < 2; ++kc)
            qf1[kc] = *reinterpret_cast<const bf16x8*>(&Q[(qt1 * 16 + lr) * DH + kc * 32 + g * 8]);
    }

    __syncthreads();   // K gload + V ds_write drained (vmcnt+lgkmcnt)

    ushort* Pw = &Plds[w * 16 * VSTRIDE];
    // zero P pad cols 208..223 once (persists across both tiles)
    {
        int row = lane >> 2, col = 208 + (lane & 3) * 4;
        *reinterpret_cast<ushort4*>(&Pw[row * VSTRIDE + col]) = make_ushort4(0, 0, 0, 0);
    }

    const int kswz0 = ((0 * 4 + g) ^ (lr & 7)) << 3;
    const int kswz1 = ((1 * 4 + g) ^ (lr & 7)) << 3;
    const float cs = 0.125f * 1.4426950408889634f;   // scale * log2(e)

    auto process = [&](int qt, bf16x8 qfa, bf16x8 qfb) {
        // QK^T (swapped): lane holds S^T[kv=t*16+g*4+rr][q=qt*16+lr]
        f32x4 s[13];
        __builtin_amdgcn_s_setprio(1);
        #pragma unroll
        for (int t = 0; t < 13; ++t) {
            f32x4 a = {};
            bf16x8 kf0 = *reinterpret_cast<const bf16x8*>(&Klds[(t * 16 + lr) * DH + kswz0]);
            a = __builtin_amdgcn_mfma_f32_16x16x32_bf16(kf0, qfa, a, 0, 0, 0);
            bf16x8 kf1 = *reinterpret_cast<const bf16x8*>(&Klds[(t * 16 + lr) * DH + kswz1]);
            a = __builtin_amdgcn_mfma_f32_16x16x32_bf16(kf1, qfb, a, 0, 0, 0);
            s[t] = a;
        }
        __builtin_amdgcn_s_setprio(0);

        float m = -1e30f;
        #pragma unroll
        for (int t = 0; t < 13; ++t) {
            #pragma unroll
            for (int rr = 0; rr < 4; ++rr) {
                int kv = t * 16 + g * 4 + rr;
                float v = (kv < MKV) ? s[t][rr] : -1e30f;
                s[t][rr] = v;
                m = fmaxf(m, v);
            }
        }
        m = fmaxf(m, __shfl_xor(m, 16));
        m = fmaxf(m, __shfl_xor(m, 32));

        float sum = 0.f;
        #pragma unroll
        for (int t = 0; t < 13; ++t) {
            #pragma unroll
            for (int rr = 0; rr < 4; ++rr) {
                float p = exp2f((s[t][rr] - m) * cs);
                s[t][rr] = p;
                sum += p;
            }
        }
        sum += __shfl_xor(sum, 16);
        sum += __shfl_xor(sum, 32);
        float inv = 1.0f / sum;

        #pragma unroll
        for (int t = 0; t < 13; ++t) {
            #pragma unroll
            for (int rr = 0; rr < 4; ++rr)
                Pw[lr * VSTRIDE + t * 16 + g * 4 + rr] = f2bf(s[t][rr] * inv);
        }
        // same-wave ds_write -> ds_read: compiler inserts lgkmcnt wait

        // PV: out^T = mfma(V^T, P); lane holds out[d=dt*16+g*4+rr][q=qt*16+lr]
        const int q = qt * 16 + lr;
        #pragma unroll
        for (int dt = 0; dt < 4; ++dt) {
            f32x4 o = {};
            __builtin_amdgcn_s_setprio(1);
            #pragma unroll
            for (int kc = 0; kc < 7; ++kc) {
                bf16x8 vf = *reinterpret_cast<const bf16x8*>(&Vlds[(dt * 16 + lr) * VSTRIDE + kc * 32 + g * 8]);
                bf16x8 pf = *reinterpret_cast<const bf16x8*>(&Pw[lr * VSTRIDE + kc * 32 + g * 8]);
                o = __builtin_amdgcn_mfma_f32_16x16x32_bf16(vf, pf, o, 0, 0, 0);
            }
            __builtin_amdgcn_s_setprio(0);
            if (q < NTOK) {
                ushort4 st = make_ushort4(f2bf(o[0]), f2bf(o[1]), f2bf(o[2]), f2bf(o[3]));
                int r = b * NTOK + q;
                *reinterpret_cast<ushort4*>(&aout[(size_t)r * CC + h * 64 + dt * 16 + g * 4]) = st;
            }
        }
    };

    process(qt0, qf0[0], qf0[1]);
    if (qt1 < 13) process(qt1, qf1[0], qf1[1]);
}

// ---------------- launch ----------------
extern "C" void kernel_launch(void* const* d_in, const int* in_sizes, int n_in,
                              void* d_out, int out_size, void* d_ws, size_t ws_size,
                              hipStream_t stream) {
    const float* x      = (const float*)d_in[0];
    const float* prompt = (const float*)d_in[1];
    const float* qkv_w  = (const float*)d_in[2];
    const float* proj_w = (const float*)d_in[3];
    const float* proj_b = (const float*)d_in[4];
    float* out = (float*)d_out;

    char* ws = (char*)d_ws;
    ushort* Xb = (ushort*)(ws + 0);          // MPAD2*768*2      = 19,660,800
    ushort* Wq = (ushort*)(ws + 19660800);   // 2304*768*2       =  3,538,944
    ushort* Wp = (ushort*)(ws + 23199744);   // 768*768*2        =  1,179,648
    ushort* qb = (ushort*)(ws + 24379392);   // 768*208*64*2     = 20,447,232
    ushort* kb = (ushort*)(ws + 44826624);   // 768*208*64*2     = 20,447,232
    ushort* vt = (ushort*)(ws + 65273856);   // 768*64*224*2     = 22,020,096
    ushort* ao = (ushort*)(ws + 87293952);   // MPAD*768*2       = 19,464,192
    // total 106,758,144 bytes

    cvt_bf16<<<dim3((MROWS * CC / 4 + 255) / 256), 256, 0, stream>>>(x, Xb, MROWS * CC / 4);
    cvt_bf16<<<dim3((3 * CC * CC / 4 + 255) / 256), 256, 0, stream>>>(qkv_w, Wq, 3 * CC * CC / 4);
    cvt_bf16<<<dim3((CC * CC / 4 + 255) / 256), 256, 0, stream>>>(proj_w, Wp, CC * CC / 4);
    prompt_scatter<<<dim3((BB * 2 * PFX * NH * DH + 255) / 256), 256, 0, stream>>>(prompt, kb, vt);

    gemm_qkv8<<<dim3(MT_QKV * NT_QKV), 512, 0, stream>>>(Xb, Wq, qb, kb, vt);
    attn_bh<<<dim3(BB * NH), 512, 0, stream>>>(qb, kb, vt, ao);
    gemm_proj<<<dim3(99 * 6), 256, 0, stream>>>(ao, Wp, proj_b, out);
}

// Round 10
// 265.499 us; speedup vs baseline: 1.1231x; 1.0484x over previous
//
#include <hip/hip_runtime.h>
#include <hip/hip_bf16.h>
#include <stdint.h>

#define NH 12
#define DH 64
#define CC 768
#define NTOK 197
#define PFX 10
#define MKV 207
#define BB 64
#define MROWS (BB * NTOK)   // 12608
#define MPAD (99 * 128)     // 12672 rows (proj A padding)
#define NT_QKV 9            // 2304 / 256
#define MT_QKV 50           // ceil(12608/256)
#define MPAD2 (MT_QKV * 256) // 12800 rows (qkv A padding)
#define KV_PAD 208          // 13 * 16
#define KV_PAD2 224         // 7 * 32
#define VSTRIDE 232         // LDS V/P stride: odd multiple of 8 -> conflict-free b128

typedef __attribute__((__ext_vector_type__(8))) short bf16x8;
typedef __attribute__((__ext_vector_type__(4))) float f32x4;

__device__ __forceinline__ ushort f2bf(float f) {
    union { float f; uint32_t u; } x; x.f = f;
    uint32_t u = x.u;
    return (ushort)((u + 0x7fffu + ((u >> 16) & 1u)) >> 16);
}

__device__ __forceinline__ void gload_lds16(const void* g, void* l) {
    __builtin_amdgcn_global_load_lds(
        (const __attribute__((address_space(1))) void*)g,
        (__attribute__((address_space(3))) void*)l, 16, 0, 0);
}

// Bijective chunked XCD swizzle (m204).
__device__ __forceinline__ int xcd_chunked(int orig, int nwg) {
    int q = nwg >> 3, r = nwg & 7;
    int xcd = orig & 7, rem = orig >> 3;
    return (xcd < r ? xcd * (q + 1) : r * (q + 1) + (xcd - r) * q) + rem;
}

// ---------------- convert fp32 -> bf16 (vectorized) ----------------
__global__ void cvt_bf16(const float* __restrict__ src, ushort* __restrict__ dst, int n4) {
    int i = blockIdx.x * 256 + threadIdx.x;
    if (i >= n4) return;
    float4 v = reinterpret_cast<const float4*>(src)[i];
    ushort4 o = make_ushort4(f2bf(v.x), f2bf(v.y), f2bf(v.z), f2bf(v.w));
    reinterpret_cast<ushort4*>(dst)[i] = o;
}

// ---------------- prompt prefix scatter ----------------
// prompt [B,2,P,H,D] fp32 -> kbuf[b,h,p,d] ; vbuf[b,h,p,d]  (both row-major [n][d])
__global__ void prompt_scatter(const float* __restrict__ prompt,
                               ushort* __restrict__ kbuf, ushort* __restrict__ vbuf) {
    int i = blockIdx.x * 256 + threadIdx.x;
    if (i >= BB * 2 * PFX * NH * DH) return;
    int d = i & 63;
    int h = (i >> 6) % NH;
    int p = (i / (64 * NH)) % PFX;
    int s = (i / (64 * NH * PFX)) & 1;
    int b = i / (64 * NH * PFX * 2);
    ushort val = f2bf(prompt[i]);
    int bh = b * NH + h;
    if (s == 0) kbuf[(bh * KV_PAD + p) * DH + d] = val;
    else        vbuf[(bh * KV_PAD + p) * DH + d] = val;
}

// ---------------- vbuf[bh][n][d] -> vt[bh][d][n] (coalesced both sides) ----------
__global__ __launch_bounds__(256) void vtrans(const ushort* __restrict__ vbuf,
                                              ushort* __restrict__ vt) {
    __shared__ __align__(16) ushort T[64][72];
    const int tid = threadIdx.x;
    const int bh = blockIdx.x;
    const ushort* src = vbuf + (size_t)bh * KV_PAD * DH;
    ushort* dst = vt + (size_t)bh * DH * KV_PAD2;
    for (int c = 0; c < 4; ++c) {
        const int nbase = c * 64;
        const int nrows = (c == 3) ? 16 : 64;
        {
            int n = tid >> 3;              // 0..31
            int db = (tid & 7) * 8;
            if (n < nrows) {
                int4 v0 = *reinterpret_cast<const int4*>(&src[(nbase + n) * DH + db]);
                const ushort* p = (const ushort*)&v0;
                #pragma unroll
                for (int e = 0; e < 8; ++e) T[db + e][n] = p[e];
            }
            if (n + 32 < nrows) {
                int4 v1 = *reinterpret_cast<const int4*>(&src[(nbase + n + 32) * DH + db]);
                const ushort* p = (const ushort*)&v1;
                #pragma unroll
                for (int e = 0; e < 8; ++e) T[db + e][n + 32] = p[e];
            }
        }
        __syncthreads();
        {
            int d = tid >> 3;              // 0..31
            int nb = (tid & 7) * 8;        // 0..56
            if (nb < nrows) {
                *reinterpret_cast<int4*>(&dst[d * KV_PAD2 + nbase + nb]) =
                    *reinterpret_cast<const int4*>(&T[d][nb]);
                *reinterpret_cast<int4*>(&dst[(d + 32) * KV_PAD2 + nbase + nb]) =
                    *reinterpret_cast<const int4*>(&T[d + 32][nb]);
            }
        }
        __syncthreads();
    }
}

// ============ GEMM-QKV: 256x256 tile, BK=64, 8 waves, counted-vmcnt pipeline ======
#define STAGE6(kt) {                                                              \
    const int bsel = (kt) & 1; const int koff = (kt) * 64;                        \
    gload_lds16(pA[0] + koff, &lds[bsel][0][0 * 4096 + w * 512]);                 \
    gload_lds16(pA[2] + koff, &lds[bsel][0][2 * 4096 + w * 512]);                 \
    gload_lds16(pB[0] + koff, &lds[bsel][1][0 * 4096 + w * 512]);                 \
    gload_lds16(pB[1] + koff, &lds[bsel][1][1 * 4096 + w * 512]);                 \
    gload_lds16(pB[2] + koff, &lds[bsel][1][2 * 4096 + w * 512]);                 \
    gload_lds16(pB[3] + koff, &lds[bsel][1][3 * 4096 + w * 512]); }

#define STAGE2(kt) {                                                              \
    const int bsel = (kt) & 1; const int koff = (kt) * 64;                        \
    gload_lds16(pA[1] + koff, &lds[bsel][0][1 * 4096 + w * 512]);                 \
    gload_lds16(pA[3] + koff, &lds[bsel][0][3 * 4096 + w * 512]); }

#define PHASE(t, p, VMSTR, DOSTAGE) {                                             \
    if (DOSTAGE) { if ((p) == 0) STAGE6((t) + 1) else STAGE2((t) + 1) }           \
    asm volatile("s_waitcnt vmcnt(" VMSTR ")" ::: "memory");                      \
    __builtin_amdgcn_s_barrier();                                                 \
    __builtin_amdgcn_sched_barrier(0);                                            \
    const ushort* Ab = &lds[(t) & 1][0][0];                                       \
    const ushort* Bb = &lds[(t) & 1][1][0];                                       \
    bf16x8 af[4][2], bf[4][2];                                                    \
    _Pragma("unroll") for (int i = 0; i < 4; ++i)                                 \
      _Pragma("unroll") for (int ks = 0; ks < 2; ++ks)                            \
        af[i][ks] = *reinterpret_cast<const bf16x8*>(                             \
            &Ab[(wm * 128 + ((p) * 4 + i) * 16 + lr) * 64 + coff[ks]]);           \
    _Pragma("unroll") for (int n = 0; n < 4; ++n)                                 \
      _Pragma("unroll") for (int ks = 0; ks < 2; ++ks)                            \
        bf[n][ks] = *reinterpret_cast<const bf16x8*>(                             \
            &Bb[(wn * 64 + n * 16 + lr) * 64 + coff[ks]]);                        \
    __builtin_amdgcn_s_setprio(1);                                                \
    _Pragma("unroll") for (int ks = 0; ks < 2; ++ks)                              \
      _Pragma("unroll") for (int i = 0; i < 4; ++i)                               \
        _Pragma("unroll") for (int n = 0; n < 4; ++n)                             \
          acc[(p) * 4 + i][n] = __builtin_amdgcn_mfma_f32_16x16x32_bf16(          \
              af[i][ks], bf[n][ks], acc[(p) * 4 + i][n], 0, 0, 0);                \
    __builtin_amdgcn_s_setprio(0);                                                \
    __builtin_amdgcn_s_barrier();                                                 \
    __builtin_amdgcn_sched_barrier(0);                                            \
}

__global__ __launch_bounds__(512, 2) void gemm_qkv8(const ushort* __restrict__ A,
                                                    const ushort* __restrict__ Bw,
                                                    ushort* __restrict__ qbuf,
                                                    ushort* __restrict__ kbuf,
                                                    ushort* __restrict__ vbuf) {
    __shared__ __align__(16) ushort lds[2][2][256 * 64];   // 128 KiB
    const int tid  = threadIdx.x;
    const int lane = tid & 63;
    const int w    = tid >> 6;              // wave 0..7
    const int wm = w >> 2, wn = w & 3;      // 2M x 4N wave grid
    const int g = lane >> 4, lr = lane & 15;
    const int wgid = xcd_chunked(blockIdx.x, gridDim.x);
    const int row0 = (wgid / NT_QKV) * 256;
    const int col0 = (wgid % NT_QKV) * 256;

    const int sr  = tid >> 3;                                  // 0..63
    const int scb = (((tid & 7) ^ ((tid >> 3) & 7)) << 3);     // ushort offset
    const int lr7 = lr & 7;
    int coff[2];
    coff[0] = ((0 * 4 + g) ^ lr7) << 3;
    coff[1] = ((1 * 4 + g) ^ lr7) << 3;

    const ushort* pA[4];
    #pragma unroll
    for (int q = 0; q < 4; ++q)
        pA[q] = A + (size_t)(row0 + q * 64 + sr) * CC + scb;
    const ushort* pB[4];
    #pragma unroll
    for (int j = 0; j < 4; ++j)
        pB[j] = Bw + (size_t)(col0 + j * 64 + sr) * CC + scb;

    f32x4 acc[8][4] = {};

    STAGE6(0)
    STAGE2(0)

    for (int t = 0; t < 11; ++t) {
        PHASE(t, 0, "8", true)
        PHASE(t, 1, "8", true)
    }
    PHASE(11, 0, "2", false)
    PHASE(11, 1, "0", false)

    // epilogue: q/k/v all coalesced [n][d]-style (32-B chunks)
    #pragma unroll
    for (int ni = 0; ni < 4; ++ni) {
        int f = col0 + wn * 64 + ni * 16 + lr;     // 0..2303
        int s   = f / CC;
        int rem = f - s * CC;
        int h = rem >> 6, d = rem & 63;
        #pragma unroll
        for (int mi = 0; mi < 8; ++mi) {
            #pragma unroll
            for (int rr = 0; rr < 4; ++rr) {
                int r = row0 + wm * 128 + mi * 16 + g * 4 + rr;
                if (r >= MROWS) continue;
                int b = r / NTOK;
                int n = r - b * NTOK;
                ushort val = f2bf(acc[mi][ni][rr]);
                int bh = b * NH + h;
                if (s == 0)      qbuf[(bh * KV_PAD + n) * DH + d] = val;
                else if (s == 1) kbuf[(bh * KV_PAD + n + PFX) * DH + d] = val;
                else             vbuf[(bh * KV_PAD + n + PFX) * DH + d] = val;
            }
        }
    }
}

// ---------------- GEMM-proj: 2-phase double-buffered 128x128 ----------------
#define GEMM_PRE(A_, B_, KDIM, NTILES)                                               \
    __shared__ __align__(16) ushort Alds0[128 * 32];                                 \
    __shared__ __align__(16) ushort Blds0[128 * 32];                                 \
    __shared__ __align__(16) ushort Alds1[128 * 32];                                 \
    __shared__ __align__(16) ushort Blds1[128 * 32];                                 \
    const int tid  = threadIdx.x;                                                    \
    const int lane = tid & 63;                                                       \
    const int wave = tid >> 6;                                                       \
    const int wm = wave >> 1, wn = wave & 1;                                         \
    const int g = lane >> 4, lr = lane & 15;                                         \
    const int wgid = xcd_chunked(blockIdx.x, gridDim.x);                             \
    const int row0 = (wgid / (NTILES)) * 128;                                        \
    const int col0 = (wgid % (NTILES)) * 128;                                        \
    const int srow = lane >> 2;                                                      \
    const int scol = (lane & 3) * 8;                                                 \
    const ushort* gA0 = &(A_)[(size_t)(row0 + wave * 16 + srow) * (KDIM) + scol];    \
    const ushort* gA1 = gA0 + (size_t)64 * (KDIM);                                   \
    const ushort* gB0 = &(B_)[(size_t)(col0 + wave * 16 + srow) * (KDIM) + scol];    \
    const ushort* gB1 = gB0 + (size_t)64 * (KDIM);                                   \
    f32x4 acc[4][4] = {};

#define GEMM_STAGE(AB, BB_, KOFF)                                                    \
    gload_lds16(gA0 + (KOFF), &(AB)[(wave * 16) * 32]);                              \
    gload_lds16(gA1 + (KOFF), &(AB)[(64 + wave * 16) * 32]);                         \
    gload_lds16(gB0 + (KOFF), &(BB_)[(wave * 16) * 32]);                             \
    gload_lds16(gB1 + (KOFF), &(BB_)[(64 + wave * 16) * 32]);

#define GEMM_COMPUTE(AB, BB_)                                                        \
    {                                                                                \
        bf16x8 af[4], bfr[4];                                                        \
        _Pragma("unroll")                                                            \
        for (int i = 0; i < 4; ++i)                                                  \
            af[i] = *reinterpret_cast<const bf16x8*>(&(AB)[(wm * 64 + i * 16 + lr) * 32 + g * 8]); \
        _Pragma("unroll")                                                            \
        for (int i = 0; i < 4; ++i)                                                  \
            bfr[i] = *reinterpret_cast<const bf16x8*>(&(BB_)[(wn * 64 + i * 16 + lr) * 32 + g * 8]); \
        _Pragma("unroll")                                                            \
        for (int mi = 0; mi < 4; ++mi)                                               \
            _Pragma("unroll")                                                        \
            for (int ni = 0; ni < 4; ++ni)                                           \
                acc[mi][ni] = __builtin_amdgcn_mfma_f32_16x16x32_bf16(af[mi], bfr[ni], acc[mi][ni], 0, 0, 0); \
    }

#define GEMM_MAIN(A_, B_, KDIM, NTILES)                                              \
    GEMM_PRE(A_, B_, KDIM, NTILES)                                                   \
    GEMM_STAGE(Alds0, Blds0, 0)                                                      \
    __syncthreads();                                                                 \
    for (int k0 = 0; k0 < (KDIM); k0 += 64) {                                        \
        GEMM_STAGE(Alds1, Blds1, k0 + 32)                                            \
        GEMM_COMPUTE(Alds0, Blds0)                                                   \
        __syncthreads();                                                             \
        if (k0 + 64 < (KDIM)) { GEMM_STAGE(Alds0, Blds0, k0 + 64) }                  \
        GEMM_COMPUTE(Alds1, Blds1)                                                   \
        __syncthreads();                                                             \
    }

__global__ __launch_bounds__(256) void gemm_proj(const ushort* __restrict__ A,
                                                 const ushort* __restrict__ Bw,
                                                 const float* __restrict__ bias,
                                                 float* __restrict__ out) {
    GEMM_MAIN(A, Bw, CC, 6)
    #pragma unroll
    for (int ni = 0; ni < 4; ++ni) {
        int o = col0 + wn * 64 + ni * 16 + lr;
        float bs = bias[o];
        #pragma unroll
        for (int mi = 0; mi < 4; ++mi) {
            #pragma unroll
            for (int rr = 0; rr < 4; ++rr) {
                int r = row0 + wm * 64 + mi * 16 + g * 4 + rr;
                if (r >= MROWS) continue;
                out[(size_t)r * CC + o] = acc[mi][ni][rr] + bs;
            }
        }
    }
}

// ================= fused attention: one 8-wave block per (b,h) =================
__global__ __launch_bounds__(512, 2) void attn_bh(const ushort* __restrict__ qbuf,
                                                  const ushort* __restrict__ kbuf,
                                                  const ushort* __restrict__ vt,
                                                  ushort* __restrict__ aout) {
    __shared__ __align__(16) ushort Klds[KV_PAD * DH];        // 26,624 B
    __shared__ __align__(16) ushort Vlds[DH * VSTRIDE];       // 29,696 B
    __shared__ __align__(16) ushort Plds[8 * 16 * VSTRIDE];   // 59,392 B
    const int tid  = threadIdx.x;
    const int lane = tid & 63;
    const int w    = tid >> 6;
    const int g = lane >> 4, lr = lane & 15;
    const int bh = blockIdx.x;               // 0..767
    const int b = bh / NH, h = bh - b * NH;

    // ---- stage K (26 x 1KB units, XOR-swizzled source, linear LDS dest) ----
    const ushort* pKsrc = kbuf + (size_t)bh * KV_PAD * DH
                        + (lane >> 3) * DH + (((lane & 7) ^ (lane >> 3)) << 3);
    #pragma unroll
    for (int u = 0; u < 4; ++u) {
        int uu = w + u * 8;
        if (uu < 26) gload_lds16(pKsrc + uu * 512, &Klds[uu * 512]);
    }

    // ---- stage V^T into padded LDS (reg path; 1792 x 16B units) ----
    const int4* vsrc = reinterpret_cast<const int4*>(vt + (size_t)bh * DH * KV_PAD2);
    #pragma unroll
    for (int k = 0; k < 4; ++k) {
        int u = tid + 512 * k;
        if (u < DH * (KV_PAD2 / 8)) {        // 1792
            int4 d = vsrc[u];
            int row  = u / (KV_PAD2 / 8);    // /28
            int colu = u - row * (KV_PAD2 / 8);
            *reinterpret_cast<int4*>(&Vlds[row * VSTRIDE + colu * 8]) = d;
        }
    }

    // ---- prefetch Q fragments for this wave's tiles ----
    const ushort* Q = qbuf + (size_t)bh * KV_PAD * DH;
    const int qt0 = w, qt1 = w + 8;          // qt1 valid iff w < 5
    bf16x8 qf0[2], qf1[2];
    #pragma unroll
    for (int kc = 0; kc < 2; ++kc)
        qf0[kc] = *reinterpret_cast<const bf16x8*>(&Q[(qt0 * 16 + lr) * DH + kc * 32 + g * 8]);
    if (qt1 < 13) {
        #pragma unroll
        for (int kc = 0; kc < 2; ++kc)
            qf1[kc] = *reinterpret_cast<const bf16x8*>(&Q[(qt1 * 16 + lr) * DH + kc * 32 + g * 8]);
    }

    __syncthreads();   // K gload + V ds_write drained

    ushort* Pw = &Plds[w * 16 * VSTRIDE];

    const int kswz0 = ((0 * 4 + g) ^ (lr & 7)) << 3;
    const int kswz1 = ((1 * 4 + g) ^ (lr & 7)) << 3;
    const float cs = 0.125f * 1.4426950408889634f;   // scale * log2(e)

    auto process = [&](int qt, bf16x8 qfa, bf16x8 qfb) {
        // re-zero P pad cols 208..223 (clobbered by previous tile's O-transpose)
        {
            int row = lane >> 2, col = 208 + (lane & 3) * 4;
            *reinterpret_cast<ushort4*>(&Pw[row * VSTRIDE + col]) = make_ushort4(0, 0, 0, 0);
        }

        // QK^T (swapped): lane holds S^T[kv=t*16+g*4+rr][q=qt*16+lr]
        f32x4 s[13];
        __builtin_amdgcn_s_setprio(1);
        #pragma unroll
        for (int t = 0; t < 13; ++t) {
            f32x4 a = {};
            bf16x8 kf0 = *reinterpret_cast<const bf16x8*>(&Klds[(t * 16 + lr) * DH + kswz0]);
            a = __builtin_amdgcn_mfma_f32_16x16x32_bf16(kf0, qfa, a, 0, 0, 0);
            bf16x8 kf1 = *reinterpret_cast<const bf16x8*>(&Klds[(t * 16 + lr) * DH + kswz1]);
            a = __builtin_amdgcn_mfma_f32_16x16x32_bf16(kf1, qfb, a, 0, 0, 0);
            s[t] = a;
        }
        __builtin_amdgcn_s_setprio(0);

        float m = -1e30f;
        #pragma unroll
        for (int t = 0; t < 13; ++t) {
            #pragma unroll
            for (int rr = 0; rr < 4; ++rr) {
                int kv = t * 16 + g * 4 + rr;
                float v = (kv < MKV) ? s[t][rr] : -1e30f;
                s[t][rr] = v;
                m = fmaxf(m, v);
            }
        }
        m = fmaxf(m, __shfl_xor(m, 16));
        m = fmaxf(m, __shfl_xor(m, 32));

        float sum = 0.f;
        #pragma unroll
        for (int t = 0; t < 13; ++t) {
            #pragma unroll
            for (int rr = 0; rr < 4; ++rr) {
                float p = exp2f((s[t][rr] - m) * cs);
                s[t][rr] = p;
                sum += p;
            }
        }
        sum += __shfl_xor(sum, 16);
        sum += __shfl_xor(sum, 32);
        float inv = 1.0f / sum;

        // packed P store: ushort4 per t (8-B aligned: 464*lr + 32*t + 8*g)
        #pragma unroll
        for (int t = 0; t < 13; ++t) {
            ushort4 pk = make_ushort4(f2bf(s[t][0] * inv), f2bf(s[t][1] * inv),
                                      f2bf(s[t][2] * inv), f2bf(s[t][3] * inv));
            *reinterpret_cast<ushort4*>(&Pw[lr * VSTRIDE + t * 16 + g * 4]) = pk;
        }

        // PV: lane holds o[dt][rr] = out[d=dt*16+g*4+rr][q=qt*16+lr]
        f32x4 o[4] = {};
        #pragma unroll
        for (int dt = 0; dt < 4; ++dt) {
            __builtin_amdgcn_s_setprio(1);
            #pragma unroll
            for (int kc = 0; kc < 7; ++kc) {
                bf16x8 vf = *reinterpret_cast<const bf16x8*>(&Vlds[(dt * 16 + lr) * VSTRIDE + kc * 32 + g * 8]);
                bf16x8 pf = *reinterpret_cast<const bf16x8*>(&Pw[lr * VSTRIDE + kc * 32 + g * 8]);
                o[dt] = __builtin_amdgcn_mfma_f32_16x16x32_bf16(vf, pf, o[dt], 0, 0, 0);
            }
            __builtin_amdgcn_s_setprio(0);
        }

        // transpose O via Pw region reused as [64][18] (9l mod 32 -> conflict-free)
        #pragma unroll
        for (int dt = 0; dt < 4; ++dt)
            #pragma unroll
            for (int rr = 0; rr < 4; ++rr)
                Pw[(dt * 16 + g * 4 + rr) * 18 + lr] = f2bf(o[dt][rr]);

        // coalesced 128-B row stores: lane = output channel h*64+lane
        const int rbase = b * NTOK + qt * 16;
        #pragma unroll
        for (int q16 = 0; q16 < 16; ++q16) {
            ushort vv = Pw[lane * 18 + q16];
            if (qt * 16 + q16 < NTOK)
                aout[(size_t)(rbase + q16) * CC + h * 64 + lane] = vv;
        }
    };

    process(qt0, qf0[0], qf0[1]);
    if (qt1 < 13) process(qt1, qf1[0], qf1[1]);
}

// ---------------- launch ----------------
extern "C" void kernel_launch(void* const* d_in, const int* in_sizes, int n_in,
                              void* d_out, int out_size, void* d_ws, size_t ws_size,
                              hipStream_t stream) {
    const float* x      = (const float*)d_in[0];
    const float* prompt = (const float*)d_in[1];
    const float* qkv_w  = (const float*)d_in[2];
    const float* proj_w = (const float*)d_in[3];
    const float* proj_b = (const float*)d_in[4];
    float* out = (float*)d_out;

    char* ws = (char*)d_ws;
    ushort* Xb = (ushort*)(ws + 0);          // MPAD2*768*2      = 19,660,800
    ushort* Wq = (ushort*)(ws + 19660800);   // 2304*768*2       =  3,538,944
    ushort* Wp = (ushort*)(ws + 23199744);   // 768*768*2        =  1,179,648
    ushort* qb = (ushort*)(ws + 24379392);   // 768*208*64*2     = 20,447,232
    ushort* kb = (ushort*)(ws + 44826624);   // 768*208*64*2     = 20,447,232
    ushort* vt = (ushort*)(ws + 65273856);   // 768*64*224*2     = 22,020,096
    // R: vbuf (gemm output, [bh][n][d]) then reused as ao (attn output) —
    // vbuf is dead after vtrans; attn writes ao afterwards. 20,447,232 B.
    ushort* vbuf = (ushort*)(ws + 87293952);
    ushort* ao   = (ushort*)(ws + 87293952);
    // total 107,741,184 bytes

    cvt_bf16<<<dim3((MROWS * CC / 4 + 255) / 256), 256, 0, stream>>>(x, Xb, MROWS * CC / 4);
    cvt_bf16<<<dim3((3 * CC * CC / 4 + 255) / 256), 256, 0, stream>>>(qkv_w, Wq, 3 * CC * CC / 4);
    cvt_bf16<<<dim3((CC * CC / 4 + 255) / 256), 256, 0, stream>>>(proj_w, Wp, CC * CC / 4);
    prompt_scatter<<<dim3((BB * 2 * PFX * NH * DH + 255) / 256), 256, 0, stream>>>(prompt, kb, vbuf);

    gemm_qkv8<<<dim3(MT_QKV * NT_QKV), 512, 0, stream>>>(Xb, Wq, qb, kb, vbuf);
    vtrans<<<dim3(BB * NH), 256, 0, stream>>>(vbuf, vt);
    attn_bh<<<dim3(BB * NH), 512, 0, stream>>>(qb, kb, vt, ao);
    gemm_proj<<<dim3(99 * 6), 256, 0, stream>>>(ao, Wp, proj_b, out);
}